// Round 6
// baseline (195.367 us; speedup 1.0000x reference)
//
#include <hip/hip_runtime.h>
#include <math.h>

typedef __attribute__((ext_vector_type(8))) short bf16x8;
typedef __attribute__((ext_vector_type(4))) short bf16x4;
typedef __attribute__((ext_vector_type(4))) float f32x4;
typedef __attribute__((ext_vector_type(16))) float f32x16;

#define MFMA16(a, b, c) __builtin_amdgcn_mfma_f32_16x16x32_bf16(a, b, c, 0, 0, 0)
#define MFMA32(a, b, c) __builtin_amdgcn_mfma_f32_32x32x16_bf16(a, b, c, 0, 0, 0)

#define GLOAD_LDS16(g, l)                                                        \
    __builtin_amdgcn_global_load_lds(                                            \
        (const __attribute__((address_space(1))) void*)(g),                      \
        (__attribute__((address_space(3))) void*)(l), 16, 0, 0)

__device__ __forceinline__ short f2bf(float f) {
    union { float f; unsigned u; } x; x.f = f;
    unsigned r = (x.u + 0x7fffu + ((x.u >> 16) & 1u)) >> 16;
    return (short)r;
}

__device__ __forceinline__ f32x16 zero16() {
    f32x16 z;
#pragma unroll
    for (int i = 0; i < 16; i++) z[i] = 0.f;
    return z;
}

// ---------------- elementwise fp32 -> bf16 ----------------
__global__ __launch_bounds__(256) void convert_bf16_kernel(
    const float* __restrict__ in, short* __restrict__ out, int n4) {
    int i = blockIdx.x * 256 + threadIdx.x;
    if (i >= n4) return;
    float4 v = ((const float4*)in)[i];
    bf16x4 o;
    o[0] = f2bf(v.x); o[1] = f2bf(v.y); o[2] = f2bf(v.z); o[3] = f2bf(v.w);
    ((bf16x4*)out)[i] = o;
}

// ------- fused transpose+convert for both weights: W[K][N] fp32 -> Wt[N][K] bf16 -----
__global__ __launch_bounds__(256) void transpose_w2_kernel(
    const float* __restrict__ Wa, const float* __restrict__ Wp,
    short* __restrict__ WaT, short* __restrict__ WpT) {
    __shared__ float tile[32][33];
    const float* W; short* Wt; int N, xb;
    if (blockIdx.x < 96) { W = Wa; Wt = WaT; N = 3072; xb = blockIdx.x; }
    else                 { W = Wp; Wt = WpT; N = 1024; xb = blockIdx.x - 96; }
    const int K = 1024;
    int c = threadIdx.x & 31, r0 = threadIdx.x >> 5;
    int n0 = xb << 5, k0 = blockIdx.y << 5;
#pragma unroll
    for (int i = 0; i < 4; i++) {
        int r = r0 + i * 8;
        tile[r][c] = W[(long)(k0 + r) * N + n0 + c];
    }
    __syncthreads();
#pragma unroll
    for (int i = 0; i < 4; i++) {
        int r = r0 + i * 8;
        Wt[(long)(n0 + r) * K + k0 + c] = f2bf(tile[c][r]);
    }
}

// ---------------- bf16 GEMM (m97 pattern): C = A[M,K] * Bt[N,K]^T + bias ----------------
// EPI 0: fp32 out[M,N].
// EPI 1 (QKV): n-blocks 0-7 -> Q rows (scaled), 8-15 -> K rows (both into qkv[4096][3072]
//              bf16 row-major, coalesced); 16-23 -> V: LDS-transpose -> VT[B,H,64,2048].
template <int EPI>
__global__ __launch_bounds__(256) void gemm_bt_kernel(
    const short* __restrict__ A, const short* __restrict__ Bt,
    const float* __restrict__ bias, float* __restrict__ outF,
    short* __restrict__ qkv, short* __restrict__ VTb,
    int M, int N, int Kdim) {
    __shared__ __align__(16) short lsAll[17408];  // lsA[8192] | lsB[8192]; V-epi: 4x64x68
    short* lsA = lsAll;
    short* lsB = lsAll + 8192;
    const int tid = threadIdx.x;
    const int lane = tid & 63, l15 = lane & 15, quad = lane >> 4;
    const int w = tid >> 6, wm = w >> 1, wn = w & 1;
    const int m0 = blockIdx.y * 128, n0 = blockIdx.x * 128;
    const int e = l15 & 7;
    const int lrow = lane >> 3;
    const int lgcol = ((lane & 7) ^ lrow) << 3;  // shorts

    f32x4 acc[4][4];
#pragma unroll
    for (int i = 0; i < 4; i++)
#pragma unroll
        for (int j = 0; j < 4; j++) acc[i][j] = (f32x4){0.f, 0.f, 0.f, 0.f};

    for (int k0 = 0; k0 < Kdim; k0 += 64) {
#pragma unroll
        for (int ii = 0; ii < 4; ii++) {
            const int i = (w << 2) + ii;
            const int grow = (i << 3) + lrow;
            GLOAD_LDS16(&A[(size_t)(m0 + grow) * Kdim + k0 + lgcol], &lsA[i * 512]);
            GLOAD_LDS16(&Bt[(size_t)(n0 + grow) * Kdim + k0 + lgcol], &lsB[i * 512]);
        }
        __syncthreads();
#pragma unroll
        for (int kk = 0; kk < 64; kk += 32) {
            const int kb = kk >> 3;
            bf16x8 af[4], bfr[4];
#pragma unroll
            for (int t = 0; t < 4; t++) {
                const int sw = (((kb + quad) ^ e) << 3);
                af[t] = *(const bf16x8*)&lsA[(wm * 64 + t * 16 + l15) * 64 + sw];
                bfr[t] = *(const bf16x8*)&lsB[(wn * 64 + t * 16 + l15) * 64 + sw];
            }
#pragma unroll
            for (int mt = 0; mt < 4; mt++)
#pragma unroll
                for (int nt = 0; nt < 4; nt++)
                    acc[mt][nt] = MFMA16(af[mt], bfr[nt], acc[mt][nt]);
        }
        __syncthreads();  // final iteration: also protects lsAll reuse in V-epilogue
    }

    if (EPI == 0) {
#pragma unroll
        for (int nt = 0; nt < 4; nt++) {
            int nn = n0 + wn * 64 + nt * 16 + l15;
            float bv = bias[nn];
#pragma unroll
            for (int mt = 0; mt < 4; mt++)
#pragma unroll
                for (int r = 0; r < 4; r++) {
                    int mm = m0 + wm * 64 + mt * 16 + quad * 4 + r;
                    outF[(long)mm * N + nn] = acc[mt][nt][r] + bv;
                }
        }
    } else if (n0 < 2048) {
        // Q or K: coalesced bf16 row stores into qkv[4096][3072]
        const float scale = (n0 < 1024) ? 0.18033688011112042f : 1.0f;  // 1/8*log2(e)
#pragma unroll
        for (int nt = 0; nt < 4; nt++) {
            int nn = n0 + wn * 64 + nt * 16 + l15;
            float bv = bias[nn];
#pragma unroll
            for (int mt = 0; mt < 4; mt++)
#pragma unroll
                for (int r = 0; r < 4; r++) {
                    int mm = m0 + wm * 64 + mt * 16 + quad * 4 + r;
                    qkv[(long)mm * 3072 + nn] = f2bf((acc[mt][nt][r] + bv) * scale);
                }
        }
    } else {
        // V: transpose via LDS -> VT[(bb*16+h)*64 + d][2048], coalesced 16B stores
        short* vt = &lsAll[w * (64 * 68)];
#pragma unroll
        for (int nt = 0; nt < 4; nt++) {
            int nn = n0 + wn * 64 + nt * 16 + l15;
            float bv = bias[nn];
#pragma unroll
            for (int mt = 0; mt < 4; mt++) {
                bf16x4 pk;
#pragma unroll
                for (int r = 0; r < 4; r++) pk[r] = f2bf(acc[mt][nt][r] + bv);
                *(bf16x4*)&vt[(nt * 16 + l15) * 68 + mt * 16 + quad * 4] = pk;
            }
        }
        const int hh = ((n0 - 2048) >> 6) + wn;
        const int bb = m0 >> 11;
        const int srow = (m0 & 2047) + wm * 64;
        const int sloc = (lane & 7) << 3;
#pragma unroll
        for (int i = 0; i < 8; i++) {
            const int d = i * 8 + (lane >> 3);
            bf16x8 vv = *(const bf16x8*)&vt[d * 68 + sloc];
            *(bf16x8*)&VTb[((size_t)(bb * 16 + hh) * 64 + d) * 2048 + srow + sloc] = vv;
        }
    }
}

// ---------------- causal flash attention: 32x32 MFMA, 4-wave blocks, 128 q/block ------
// Wave = 32 q rows (q = qt*128 + w*32 + (lane&31)). 64-key chunks double-buffered in
// LDS (XOR-swizzled). S^T = K*Q^T and O^T = V^T*P^T via mfma_32x32x16 — 2x the MACs
// per A-fragment byte of 16x16x32, halving the LDS-read bottleneck. No max-tracking
// (scores bounded, see R5); per-lane partial l, one shfl at the end.
// Layouts: C/D col=lane&31, row=(reg&3)+8*(reg>>2)+4*(lane>>5); A/B k=(lane>>5)*8+j.
__global__ __launch_bounds__(256, 3) void attn_kernel(
    const short* __restrict__ qkv, const short* __restrict__ VT,
    short* __restrict__ Ao) {
    __shared__ __align__(16) short Kt[2][64 * 64];  // 16 KB
    __shared__ __align__(16) short Vt[2][64 * 64];  // 16 KB
    __shared__ __align__(16) short Pt[4][32 * 64];  // 16 KB (per-wave private)
    const int tid = threadIdx.x;
    const int lane = tid & 63, col = lane & 31, hi = lane >> 5, w = tid >> 6;
    const int bx = blockIdx.x;
    const int qt = 15 - (bx >> 5);  // heavy q-tiles first
    const int hb = bx & 31;         // b*16 + h
    const int b = hb >> 4, h = hb & 15;
    const size_t rowbase = (size_t)b * 2048 * 3072 + h * 64;
    const short* Qb = qkv + rowbase;          // q row: + qs*3072 + d
    const short* Kb = qkv + rowbase + 1024;   // k row: + ks*3072 + d
    const short* Vh = VT + (size_t)hb * 64 * 2048;  // [64][2048]
    short* Pw = &Pt[w][0];

    // staging geometry (rows 0..63 of a 64x64 tile, swizzled phys16Bcol = log ^ (row&7))
    const int srow0 = tid >> 3, sc40 = (tid & 7) ^ (srow0 & 7);
    const int srow1 = srow0 + 32, sc41 = (tid & 7) ^ (srow1 & 7);
    const int sdst0 = srow0 * 64 + ((tid & 7) << 3);
    const int sdst1 = srow1 * 64 + ((tid & 7) << 3);

    const int qloc = w * 32 + col;       // q within the 128-row block
    const int qglob = qt * 128 + qloc;

    // Q fragments (B-operand: n=col=q, k = kc*16 + hi*8 + j = d)
    bf16x8 qf[4];
#pragma unroll
    for (int kc = 0; kc < 4; kc++)
        qf[kc] = *(const bf16x8*)&Qb[(long)qglob * 3072 + kc * 16 + hi * 8];

    float l = 0.f;  // per-lane partial denominator
    f32x16 o[2];
    o[0] = zero16(); o[1] = zero16();

    const int nc = 2 * qt + 2;           // 64-key chunks
    const int ca = 2 * qt + (w >> 1);    // this wave's last (diagonal) chunk

    // stage chunk 0
    *(bf16x8*)&Kt[0][sdst0] = *(const bf16x8*)&Kb[(size_t)srow0 * 3072 + sc40 * 8];
    *(bf16x8*)&Kt[0][sdst1] = *(const bf16x8*)&Kb[(size_t)srow1 * 3072 + sc41 * 8];
    *(bf16x8*)&Vt[0][sdst0] = *(const bf16x8*)&Vh[srow0 * 2048 + sc40 * 8];
    *(bf16x8*)&Vt[0][sdst1] = *(const bf16x8*)&Vh[srow1 * 2048 + sc41 * 8];
    __syncthreads();

    for (int c = 0; c < nc; c++) {
        const short* Kc = &Kt[c & 1][0];
        const short* Vc = &Vt[c & 1][0];
        const bool more = (c + 1 < nc);
        bf16x8 kr0, kr1, vr0, vr1;
        if (more) {
            const int k2 = (c + 1) * 64;
            kr0 = *(const bf16x8*)&Kb[(size_t)(k2 + srow0) * 3072 + sc40 * 8];
            kr1 = *(const bf16x8*)&Kb[(size_t)(k2 + srow1) * 3072 + sc41 * 8];
            vr0 = *(const bf16x8*)&Vh[srow0 * 2048 + k2 + sc40 * 8];
            vr1 = *(const bf16x8*)&Vh[srow1 * 2048 + k2 + sc41 * 8];
        }

        if (c <= ca) {  // wave-uniform skip of fully-masked chunks
            // S^T = K*Q^T: two 32-key tiles; A = K rows (key), B = Q^T
            f32x16 s[2];
#pragma unroll
            for (int t = 0; t < 2; t++) {
                f32x16 z = zero16();
#pragma unroll
                for (int kc = 0; kc < 4; kc++) {
                    const int row = t * 32 + col;
                    bf16x8 kf = *(const bf16x8*)&Kc[row * 64 + (((kc * 2 + hi) ^ (row & 7)) << 3)];
                    z = MFMA32(kf, qf[kc], z);
                }
                s[t] = z;
            }

            if (c == ca) {  // diagonal chunk: key = c*64 + t*32 + row vs q = qglob
#pragma unroll
                for (int t = 0; t < 2; t++) {
                    const int thresh = qloc + qt * 128 - c * 64 - t * 32;
#pragma unroll
                    for (int g = 0; g < 4; g++)
#pragma unroll
                        for (int r2 = 0; r2 < 4; r2++) {
                            const int row = r2 + 8 * g + 4 * hi;
                            if (row > thresh) s[t][g * 4 + r2] = -INFINITY;
                        }
                }
            }

            // P = exp2(s); accumulate per-lane l; write P[q][key] (swizzled) as bf16x4
#pragma unroll
            for (int t = 0; t < 2; t++) {
#pragma unroll
                for (int g = 0; g < 4; g++) {
                    bf16x4 pw;
#pragma unroll
                    for (int r2 = 0; r2 < 4; r2++) {
                        float pv = __builtin_amdgcn_exp2f(s[t][g * 4 + r2]);
                        l += pv;
                        pw[r2] = f2bf(pv);
                    }
                    *(bf16x4*)&Pw[col * 64 + (((t * 4 + g) ^ (col & 7)) << 3) + hi * 4] = pw;
                }
            }

            // P^T as B-operand: n=col=q, k = kc2*16 + hi*8 + j = key
            bf16x8 pf[4];
#pragma unroll
            for (int kc2 = 0; kc2 < 4; kc2++)
                pf[kc2] = *(const bf16x8*)&Pw[col * 64 + (((kc2 * 2 + hi) ^ (col & 7)) << 3)];

            // O^T = V^T * P^T: A = V^T rows (d = dt*32+col), k = key slice
#pragma unroll
            for (int dt = 0; dt < 2; dt++) {
                const int vrow = dt * 32 + col;
#pragma unroll
                for (int kc2 = 0; kc2 < 4; kc2++) {
                    bf16x8 vf = *(const bf16x8*)&Vc[vrow * 64 + (((kc2 * 2 + hi) ^ (vrow & 7)) << 3)];
                    o[dt] = MFMA32(vf, pf[kc2], o[dt]);
                }
            }
        }

        if (more) {
            short* Kn = &Kt[(c + 1) & 1][0];
            short* Vn = &Vt[(c + 1) & 1][0];
            *(bf16x8*)&Kn[sdst0] = kr0;
            *(bf16x8*)&Kn[sdst1] = kr1;
            *(bf16x8*)&Vn[sdst0] = vr0;
            *(bf16x8*)&Vn[sdst1] = vr1;
        }
        __syncthreads();
    }

    // denominator: lane and lane^32 hold complementary key rows for the same q
    l += __shfl_xor(l, 32);
    const float rl = 1.f / l;

    // O^T: row = (reg&3)+8*(reg>>2)+4*hi = d within dt tile, col = q
    const long base = ((long)(b * 2048 + qglob)) * 1024 + h * 64;
#pragma unroll
    for (int dt = 0; dt < 2; dt++) {
#pragma unroll
        for (int g = 0; g < 4; g++) {
            bf16x4 wv;
#pragma unroll
            for (int r2 = 0; r2 < 4; r2++) wv[r2] = f2bf(o[dt][g * 4 + r2] * rl);
            *(bf16x4*)&Ao[base + dt * 32 + g * 8 + hi * 4] = wv;
        }
    }
}

extern "C" void kernel_launch(void* const* d_in, const int* in_sizes, int n_in,
                              void* d_out, int out_size, void* d_ws, size_t ws_size,
                              hipStream_t stream) {
    const float* hs = (const float*)d_in[0];
    const float* W_attn = (const float*)d_in[1];
    const float* b_attn = (const float*)d_in[2];
    const float* W_proj = (const float*)d_in[3];
    const float* b_proj = (const float*)d_in[4];
    float* out = (float*)d_out;

    char* ws = (char*)d_ws;
    short* hs_bf = (short*)ws;                       // 4096x1024 bf16 (8 MB)
    short* attn_o = hs_bf;                           // alias: hs_bf dead after qkv gemm
    short* WaT = (short*)(ws + 8u * 1024 * 1024);    // 3072x1024 bf16 (6 MB)
    short* WpT = (short*)(ws + 14u * 1024 * 1024);   // 1024x1024 bf16 (2 MB)
    short* qkv = (short*)(ws + 16u * 1024 * 1024);   // [4096][3072] bf16 (24 MB)
    short* VTb = (short*)(ws + 40u * 1024 * 1024);   // [2,16,64,2048] bf16 (8 MB)

    convert_bf16_kernel<<<4096, 256, 0, stream>>>(hs, hs_bf, 1048576);
    transpose_w2_kernel<<<dim3(128, 32), 256, 0, stream>>>(W_attn, W_proj, WaT, WpT);
    gemm_bt_kernel<1><<<dim3(24, 32), 256, 0, stream>>>(
        hs_bf, WaT, b_attn, nullptr, qkv, VTb, 4096, 3072, 1024);
    attn_kernel<<<512, 256, 0, stream>>>(qkv, VTb, attn_o);
    gemm_bt_kernel<0><<<dim3(8, 32), 256, 0, stream>>>(
        attn_o, WpT, b_proj, out, nullptr, nullptr, 4096, 1024, 1024);
}